// Round 2
// baseline (45.734 us; speedup 1.0000x reference)
//
#include <hip/hip_runtime.h>

// PhraseModel: two VQ argmins (z, z_pre vs codebook) + phrase gather + sum.
// ALL float tensors are float32 (per reference); pos is int32.
// argmin_k ||z-c||^2 == argmin_k (||c||^2 - 2 z.c)  (||z||^2 constant per row).
// Pure f32 VALU dots to match np reference numerics (no fp32 MFMA on CDNA4).

#define BHALF  4096   // rows per tensor
#define D_DIM  510
#define K_CODES 128

// ---------------- kernel 1: codebook row norms ----------------
__global__ void cnorm_kernel(const float* __restrict__ cb,
                             float* __restrict__ cnorm) {
    const int k = blockIdx.x;     // 0..127
    const int l = threadIdx.x;    // 0..63
    float s = 0.f;
    for (int i = l; i < D_DIM; i += 64) {
        float v = cb[(size_t)k * D_DIM + i];
        s = fmaf(v, v, s);
    }
    #pragma unroll
    for (int m = 1; m < 64; m <<= 1) s += __shfl_xor(s, m, 64);
    if (l == 0) cnorm[k] = s;
}

// ---------------- kernel 2: f32 distance + argmin ----------------
// 512 blocks x 256 threads (4 waves). Block rows = 16 (wave w owns rows
// row0+4w .. +4). Lane l owns codes {l, l+64}. Codebook+z chunks staged
// in LDS (stride 66 floats: cb b64 reads -> 4 lanes/bank, conflict-free).
__launch_bounds__(256)
__global__ void argmin_kernel(const float* __restrict__ z,
                              const float* __restrict__ zp,
                              const float* __restrict__ cb,
                              const float* __restrict__ cnorm,
                              int* __restrict__ kbest) {
    constexpr int KC = 64, LDSW = KC + 2;          // pad to 66 floats
    __shared__ float cb_lds[K_CODES][LDSW];        // 33.8 KB
    __shared__ float z_lds[16][LDSW];              //  4.2 KB

    const int tid = threadIdx.x;
    const int l = tid & 63, w = tid >> 6;
    const int row0 = blockIdx.x * 16;
    const float* A = (row0 < BHALF)
        ? z + (size_t)row0 * D_DIM
        : zp + (size_t)(row0 - BHALF) * D_DIM;

    float acc0[4] = {0.f, 0.f, 0.f, 0.f};   // code l
    float acc1[4] = {0.f, 0.f, 0.f, 0.f};   // code l+64

    for (int k0 = 0; k0 < D_DIM; k0 += KC) {
        // ---- stage cb chunk: 128x64 f32 = 4096 float2, 16 per thread ----
        #pragma unroll
        for (int i = 0; i < 16; ++i) {
            const int f2 = tid + 256 * i;              // 0..4095
            const int c = f2 >> 5;                     // 0..127
            const int kk = (f2 & 31) * 2;              // 0..62
            const int col = k0 + kk;
            float2 v = make_float2(0.f, 0.f);
            if (col < D_DIM)                           // col even, D even -> col+1 ok
                v = *(const float2*)(cb + (size_t)c * D_DIM + col);
            *(float2*)&cb_lds[c][kk] = v;
        }
        // ---- stage z chunk: 16x64 f32 = 512 float2, 2 per thread ----
        #pragma unroll
        for (int i = 0; i < 2; ++i) {
            const int f2 = tid + 256 * i;              // 0..511
            const int r = f2 >> 5;                     // 0..15
            const int kk = (f2 & 31) * 2;
            const int col = k0 + kk;
            float2 v = make_float2(0.f, 0.f);
            if (col < D_DIM)
                v = *(const float2*)(A + (size_t)r * D_DIM + col);
            *(float2*)&z_lds[r][kk] = v;
        }
        __syncthreads();

        const int klen = min(KC, D_DIM - k0);          // 64 or 62 (even)
        #pragma unroll 2
        for (int k = 0; k < klen; k += 2) {
            const float2 c0 = *(const float2*)&cb_lds[l][k];
            const float2 c1 = *(const float2*)&cb_lds[l + 64][k];
            #pragma unroll
            for (int r = 0; r < 4; ++r) {
                const float2 zz = *(const float2*)&z_lds[w * 4 + r][k];
                acc0[r] = fmaf(zz.y, c0.y, fmaf(zz.x, c0.x, acc0[r]));
                acc1[r] = fmaf(zz.y, c1.y, fmaf(zz.x, c1.x, acc1[r]));
            }
        }
        __syncthreads();
    }

    // ---- epilogue: d2 = ||c||^2 - 2 z.c ; argmin with first-index ties ----
    const float cn0 = cnorm[l], cn1 = cnorm[l + 64];
    #pragma unroll
    for (int r = 0; r < 4; ++r) {
        float bv = cn0 - 2.f * acc0[r];
        int   bi = l;
        const float d1 = cn1 - 2.f * acc1[r];
        if (d1 < bv) { bv = d1; bi = l + 64; }         // tie keeps lower (l)
        #pragma unroll
        for (int m = 1; m < 64; m <<= 1) {
            const float ov = __shfl_xor(bv, m, 64);
            const int   oi = __shfl_xor(bi, m, 64);
            if (ov < bv || (ov == bv && oi < bi)) { bv = ov; bi = oi; }
        }
        if (l == 0) kbest[row0 + w * 4 + r] = bi;
    }
}

// ---------------- kernel 3: gather + add (f32) ----------------
__global__ void gather_kernel(const float* __restrict__ cb,
                              const float* __restrict__ ph,
                              const int* __restrict__ pos,
                              const int* __restrict__ kbest,
                              float* __restrict__ out) {
    const int b = blockIdx.x;
    const int t = threadIdx.x;
    const int kz  = kbest[b];
    const int kzp = kbest[BHALF + b];
    const int p   = pos[b];
    if (t < D_DIM / 2) {   // 255 float2 per row
        const float2 a = *(const float2*)(cb + (size_t)kz  * D_DIM + 2 * t);
        const float2 c = *(const float2*)(cb + (size_t)kzp * D_DIM + 2 * t);
        const float2 e = *(const float2*)(ph + (size_t)p   * D_DIM + 2 * t);
        float2 o;
        o.x = a.x + c.x + e.x;
        o.y = a.y + c.y + e.y;
        *(float2*)(out + (size_t)b * D_DIM + 2 * t) = o;
    }
}

extern "C" void kernel_launch(void* const* d_in, const int* in_sizes, int n_in,
                              void* d_out, int out_size, void* d_ws, size_t ws_size,
                              hipStream_t stream) {
    const float* z  = (const float*)d_in[0];
    const float* zp = (const float*)d_in[1];
    const float* cb = (const float*)d_in[2];
    const float* ph = (const float*)d_in[3];
    const int*   pos = (const int*)d_in[4];
    float* out = (float*)d_out;

    int*   kbest = (int*)d_ws;                                    // 8192 ints
    float* cnorm = (float*)((char*)d_ws + 2 * BHALF * sizeof(int));

    cnorm_kernel<<<K_CODES, 64, 0, stream>>>(cb, cnorm);
    argmin_kernel<<<(2 * BHALF) / 16, 256, 0, stream>>>(z, zp, cb, cnorm, kbest);
    gather_kernel<<<BHALF, 256, 0, stream>>>(cb, ph, pos, kbest, out);
}

// Round 3
// 44.411 us; speedup vs baseline: 1.0298x; 1.0298x over previous
//
#include <hip/hip_runtime.h>

// PhraseModel: two VQ argmins (z, z_pre vs codebook) + phrase gather + sum.
// f32 throughout (matches np reference numerics; no fp32 MFMA on CDNA4).
// Round 3: VALU-balanced register blocking (4 codes x 4 rows per lane),
// z broadcasts cheap, cb reads pair-shared; gather fused into main kernel.

#define BHALF  4096
#define D_DIM  510
#define K_CODES 128
#define LSW    66      // LDS row stride (floats): even (b64-aligned), 66%32=2

// ---------------- kernel 1: codebook row norms (proven in round 2) --------
__global__ void cnorm_kernel(const float* __restrict__ cb,
                             float* __restrict__ cnorm) {
    const int k = blockIdx.x;     // 0..127
    const int l = threadIdx.x;    // 0..63
    float s = 0.f;
    for (int i = l; i < D_DIM; i += 64) {
        float v = cb[(size_t)k * D_DIM + i];
        s = fmaf(v, v, s);
    }
    #pragma unroll
    for (int m = 1; m < 64; m <<= 1) s += __shfl_xor(s, m, 64);
    if (l == 0) cnorm[k] = s;
}

// ---------------- kernel 2: fused distance + argmin + gather --------------
// 256 blocks x 512 threads (8 waves). Block: output rows r0..r0+16, i.e.
// M-rows 0..16 = z[r0..r0+16], 16..32 = zp[r0..r0+16].
// Wave wu: row-group wu&3, k-half wu>>2. Lane: l32=lane&31 owns codes
// {l32+32j}, half s=lane>>5 picks rows (wu&3)*8 + s*4 + r.
__launch_bounds__(512, 2)
__global__ void fused_kernel(const float* __restrict__ z,
                             const float* __restrict__ zp,
                             const float* __restrict__ cb,
                             const float* __restrict__ ph,
                             const int* __restrict__ pos,
                             const float* __restrict__ cnorm,
                             float* __restrict__ out) {
    __shared__ float cb_lds[K_CODES][LSW];  // 33.8 KB
    __shared__ float z_lds[32][LSW];        //  8.4 KB
    __shared__ float sm[4][64][16];         // 16.4 KB (k-half merge)
    __shared__ int   kb[32];

    const int tid  = threadIdx.x;
    const int lane = tid & 63;
    const int wu   = __builtin_amdgcn_readfirstlane(tid >> 6); // 0..7
    const int l32  = lane & 31;
    const int s    = lane >> 5;
    const int wu3  = wu & 3;
    const int kh   = wu >> 2;
    const int r0   = blockIdx.x * 16;
    const int rowb = wu3 * 8 + s * 4;       // first of this lane's 4 M-rows

    float acc[4][4];                         // [code j][row r]
    #pragma unroll
    for (int j = 0; j < 4; ++j)
        #pragma unroll
        for (int r = 0; r < 4; ++r) acc[j][r] = 0.f;

    for (int kc = 0; kc < 8; ++kc) {
        const int k0 = kc * 64;
        // ---- stage z/zp tile: 32 rows x 64 cols = 1024 float2 ----
        #pragma unroll
        for (int i = 0; i < 2; ++i) {
            const int f2 = tid + 512 * i;
            const int m  = f2 >> 5;              // 0..31
            const int kk = (f2 & 31) * 2;
            const int col = k0 + kk;
            const float* base = (m < 16)
                ? z  + (size_t)(r0 + m) * D_DIM
                : zp + (size_t)(r0 + m - 16) * D_DIM;
            float2 v = make_float2(0.f, 0.f);
            if (col < D_DIM) v = *(const float2*)(base + col);
            *(float2*)&z_lds[m][kk] = v;
        }
        // ---- stage cb tile: 128 x 64 = 4096 float2 ----
        #pragma unroll
        for (int i = 0; i < 8; ++i) {
            const int f2 = tid + 512 * i;
            const int c  = f2 >> 5;              // 0..127
            const int kk = (f2 & 31) * 2;
            const int col = k0 + kk;
            float2 v = make_float2(0.f, 0.f);
            if (col < D_DIM) v = *(const float2*)(cb + (size_t)c * D_DIM + col);
            *(float2*)&cb_lds[c][kk] = v;
        }
        __syncthreads();

        const int colbase = kh * 32;
        #pragma unroll
        for (int it = 0; it < 16; ++it) {
            const int col = colbase + it * 2;
            float2 cv[4], zv[4];
            #pragma unroll
            for (int j = 0; j < 4; ++j)
                cv[j] = *(const float2*)&cb_lds[l32 + 32 * j][col];
            #pragma unroll
            for (int r = 0; r < 4; ++r)
                zv[r] = *(const float2*)&z_lds[rowb + r][col];
            #pragma unroll
            for (int j = 0; j < 4; ++j)
                #pragma unroll
                for (int r = 0; r < 4; ++r)
                    acc[j][r] = fmaf(zv[r].y, cv[j].y,
                                fmaf(zv[r].x, cv[j].x, acc[j][r]));
        }
        __syncthreads();
    }

    // ---- merge k-halves: waves 4-7 export, waves 0-3 accumulate ----
    if (kh == 1) {
        #pragma unroll
        for (int j = 0; j < 4; ++j)
            #pragma unroll
            for (int r = 0; r < 4; ++r)
                sm[wu3][lane][j * 4 + r] = acc[j][r];
    }
    __syncthreads();
    if (kh == 0) {
        #pragma unroll
        for (int j = 0; j < 4; ++j)
            #pragma unroll
            for (int r = 0; r < 4; ++r)
                acc[j][r] += sm[wu3][lane][j * 4 + r];

        float cnv[4];
        #pragma unroll
        for (int j = 0; j < 4; ++j) cnv[j] = cnorm[l32 + 32 * j];

        // per-row argmin: local over 4 codes (ascending index -> ties keep
        // lower), then 32-lane shuffle reduce with lexicographic tie-break.
        #pragma unroll
        for (int r = 0; r < 4; ++r) {
            float bv = cnv[0] - 2.f * acc[0][r];
            int   bi = l32;
            #pragma unroll
            for (int j = 1; j < 4; ++j) {
                const float d = cnv[j] - 2.f * acc[j][r];
                if (d < bv) { bv = d; bi = l32 + 32 * j; }
            }
            #pragma unroll
            for (int m = 1; m < 32; m <<= 1) {
                const float ov = __shfl_xor(bv, m, 64);
                const int   oi = __shfl_xor(bi, m, 64);
                if (ov < bv || (ov == bv && oi < bi)) { bv = ov; bi = oi; }
            }
            if (l32 == 0) kb[rowb + r] = bi;
        }
    }
    __syncthreads();

    // ---- fused gather: 16 output rows, 32 threads per row ----
    const int i   = tid >> 5;          // 0..15
    const int g32 = tid & 31;
    const int kz  = kb[i];
    const int kzp = kb[16 + i];
    const int pp  = pos[r0 + i];
    const float* a = cb + (size_t)kz  * D_DIM;
    const float* b = cb + (size_t)kzp * D_DIM;
    const float* e = ph + (size_t)pp  * D_DIM;
    float* o = out + (size_t)(r0 + i) * D_DIM;
    #pragma unroll
    for (int itg = 0; itg < 8; ++itg) {
        const int col = g32 * 2 + itg * 64;
        if (col < D_DIM) {
            const float2 va = *(const float2*)(a + col);
            const float2 vb = *(const float2*)(b + col);
            const float2 ve = *(const float2*)(e + col);
            float2 vo;
            vo.x = va.x + vb.x + ve.x;
            vo.y = va.y + vb.y + ve.y;
            *(float2*)(o + col) = vo;
        }
    }
}

extern "C" void kernel_launch(void* const* d_in, const int* in_sizes, int n_in,
                              void* d_out, int out_size, void* d_ws, size_t ws_size,
                              hipStream_t stream) {
    const float* z  = (const float*)d_in[0];
    const float* zp = (const float*)d_in[1];
    const float* cb = (const float*)d_in[2];
    const float* ph = (const float*)d_in[3];
    const int*   pos = (const int*)d_in[4];
    float* out = (float*)d_out;

    float* cnorm = (float*)d_ws;   // 128 floats

    cnorm_kernel<<<K_CODES, 64, 0, stream>>>(cb, cnorm);
    fused_kernel<<<BHALF / 16, 512, 0, stream>>>(z, zp, cb, ph, pos, cnorm, out);
}

// Round 5
// 29.379 us; speedup vs baseline: 1.5567x; 1.5117x over previous
//
#include <hip/hip_runtime.h>

// PhraseModel: two VQ argmins (z, z_pre vs codebook) + phrase gather + sum.
// Round 5 (= round 4 with compile fix): bf16 hi/lo split MFMA ranking
// (3 exact products in f32, ~2e-4 dot error) + exact-f32 top-2 refinement;
// gather fused. Codebook pre-converted once into ws as the pre-swizzled LDS
// image: main kernel stages it linearly via global_load_lds and reads frags
// with XOR-swizzled ds_read_b128 (bank-balanced).

#define BHALF 4096
#define D 510
#define K_CODES 128
#define CHUNK_BYTES 65536            // per-chunk LDS image: 32KB hi + 32KB lo
#define WS_NEED (512 + 4 * CHUNK_BYTES)

using f32x4  = __attribute__((ext_vector_type(4))) float;
using bf16x8 = __attribute__((ext_vector_type(8))) short;
using us16x8 = __attribute__((ext_vector_type(8))) unsigned short;

__device__ __forceinline__ unsigned short f2bf(float f) {
    union { float f; unsigned int u; } v; v.f = f;
    unsigned int u = v.u;
    return (unsigned short)((u + 0x7FFFu + ((u >> 16) & 1u)) >> 16);  // RTNE
}
__device__ __forceinline__ float bf2f(unsigned short h) {
    union { unsigned int u; float f; } v; v.u = ((unsigned int)h) << 16;
    return v.f;
}
__device__ __forceinline__ bool lexlt(float va, int ia, float vb, int ib) {
    return va < vb || (va == vb && ia < ib);
}

// ---------------- prep: cnorm + pre-swizzled bf16 hi/lo codebook image ----
// 128 blocks x 64 threads; block = one code row.
__global__ void prep_kernel(const float* __restrict__ cb,
                            float* __restrict__ cnorm,
                            char* __restrict__ ws_cb) {
    const int code = blockIdx.x;
    const int l = threadIdx.x;
    const int swz = (code & 7) << 4;
    float s = 0.f;
    #pragma unroll
    for (int i = 0; i < 8; ++i) {
        const int k = l + 64 * i;                 // 0..511 (pad 510,511 -> 0)
        const float v = (k < D) ? cb[(size_t)code * D + k] : 0.f;
        s = fmaf(v, v, s);
        const unsigned short hi = f2bf(v);
        const unsigned short lo = f2bf(v - bf2f(hi));
        const size_t base = (size_t)(k >> 7) * CHUNK_BYTES + (size_t)code * 256;
        const int off = ((k & 127) * 2) ^ swz;    // XOR bits 4-6: stays in row
        *(unsigned short*)(ws_cb + base + off) = hi;
        *(unsigned short*)(ws_cb + base + 32768 + off) = lo;
    }
    #pragma unroll
    for (int m = 1; m < 64; m <<= 1) s += __shfl_xor(s, m, 64);
    if (l == 0) cnorm[code] = s;
}

// ---------------- main: MFMA distances + top2 + exact refine + gather -----
// 512 blocks x 256 threads (4 waves). Block = 8 z rows + 8 zp rows (M=16),
// all 128 codes. Wave wn owns codes wn*32..+32 (2 16x16 frags). K: 4 chunks
// of 128. LDS: cb image 64KB + z hi/lo 8KB = 72KB -> 2 blocks/CU.
__launch_bounds__(256, 2)
__global__ void main_kernel(const float* __restrict__ z,
                            const float* __restrict__ zp,
                            const float* __restrict__ cb,
                            const float* __restrict__ ph,
                            const int* __restrict__ pos,
                            const float* __restrict__ cnorm,
                            const char* __restrict__ ws_cb,
                            float* __restrict__ out) {
    __shared__ __align__(1024) char lds[73728];   // 64KB cb + 4KB z_hi + 4KB z_lo

    const int tid  = threadIdx.x;
    const int lane = tid & 63;
    const int wn   = __builtin_amdgcn_readfirstlane(tid >> 6);  // 0..3
    const int r0   = blockIdx.x * 8;

    // z staging coords: 16 threads per row, 8 cols each
    const int zrow = tid >> 4;                    // 0..15
    const int ks8  = (tid & 15) * 8;              // col block within chunk
    const int zswz = (zrow & 7) << 4;
    const float* zsrc = (zrow < 8) ? z  + (size_t)(r0 + zrow) * D
                                   : zp + (size_t)(r0 + zrow - 8) * D;

    // MFMA frag coords
    const int l15  = lane & 15;
    const int kg16 = (lane >> 4) * 16;            // k-group byte offset
    const int arow = l15;
    const int aswz = (arow & 7) << 4;
    const int code0 = wn * 32 + l15;
    const int code1 = code0 + 16;
    const int bswz  = (code0 & 7) << 4;           // (code+16)&7 == code&7
    const char* zhi_p = lds + 65536 + arow * 256;
    const char* zlo_p = zhi_p + 4096;
    const char* b0_p  = lds + code0 * 256;
    const char* b1_p  = lds + code1 * 256;

    f32x4 acc0 = {0.f, 0.f, 0.f, 0.f};
    f32x4 acc1 = {0.f, 0.f, 0.f, 0.f};

    for (int c = 0; c < 4; ++c) {
        if (c > 0) __syncthreads();               // prev chunk reads done
        // ---- stage cb chunk image: 64KB linear copy via global_load_lds ----
        {
            const char* gbase = ws_cb + (size_t)c * CHUNK_BYTES;
            #pragma unroll
            for (int i = 0; i < 16; ++i) {
                __builtin_amdgcn_global_load_lds(
                    (const __attribute__((address_space(1))) void*)
                        (gbase + (size_t)(i * 256 + tid) * 16),
                    (__attribute__((address_space(3))) void*)
                        (lds + (size_t)(i * 256 + (tid & ~63)) * 16),
                    16, 0, 0);
            }
        }
        // ---- stage z chunk: load f32, split hi/lo, swizzled 16B writes ----
        {
            const int ck0 = c * 128;
            float v[8];
            #pragma unroll
            for (int j = 0; j < 4; ++j) {
                const int col = ck0 + ks8 + 2 * j;
                float2 t2 = make_float2(0.f, 0.f);
                if (col < D) t2 = *(const float2*)(zsrc + col);
                v[2 * j] = t2.x; v[2 * j + 1] = t2.y;
            }
            us16x8 hi, lo;
            #pragma unroll
            for (int j = 0; j < 8; ++j) {
                const unsigned short h = f2bf(v[j]);
                hi[j] = h;
                lo[j] = f2bf(v[j] - bf2f(h));
            }
            const int off = zrow * 256 + ((ks8 * 2) ^ zswz);  // ks8*2 % 16 == 0
            *(us16x8*)(lds + 65536 + off) = hi;
            *(us16x8*)(lds + 65536 + 4096 + off) = lo;
        }
        __syncthreads();

        // ---- MFMA: 4 k-steps x (2 frags x 3 products) ----
        #pragma unroll
        for (int s = 0; s < 4; ++s) {
            const int kb = s * 64 + kg16;
            bf16x8 a_hi = *(const bf16x8*)(zhi_p + (kb ^ aswz));
            bf16x8 a_lo = *(const bf16x8*)(zlo_p + (kb ^ aswz));
            bf16x8 b0h  = *(const bf16x8*)(b0_p + (kb ^ bswz));
            bf16x8 b0l  = *(const bf16x8*)(b0_p + 32768 + (kb ^ bswz));
            bf16x8 b1h  = *(const bf16x8*)(b1_p + (kb ^ bswz));
            bf16x8 b1l  = *(const bf16x8*)(b1_p + 32768 + (kb ^ bswz));
            acc0 = __builtin_amdgcn_mfma_f32_16x16x32_bf16(a_hi, b0h, acc0, 0, 0, 0);
            acc1 = __builtin_amdgcn_mfma_f32_16x16x32_bf16(a_hi, b1h, acc1, 0, 0, 0);
            acc0 = __builtin_amdgcn_mfma_f32_16x16x32_bf16(a_hi, b0l, acc0, 0, 0, 0);
            acc1 = __builtin_amdgcn_mfma_f32_16x16x32_bf16(a_hi, b1l, acc1, 0, 0, 0);
            acc0 = __builtin_amdgcn_mfma_f32_16x16x32_bf16(a_lo, b0h, acc0, 0, 0, 0);
            acc1 = __builtin_amdgcn_mfma_f32_16x16x32_bf16(a_lo, b1h, acc1, 0, 0, 0);
        }
    }
    __syncthreads();

    // ---- epilogue scratch aliased onto LDS (cb image reads are done) ----
    float* smv1 = (float*)lds;             // [4][16]
    int*   smi1 = (int*)(lds + 256);
    float* smv2 = (float*)(lds + 512);
    int*   smi2 = (int*)(lds + 768);
    int*   kb2  = (int*)(lds + 1024);      // [16][2]
    float* refd = (float*)(lds + 1152);    // [32]
    int*   kbf  = (int*)(lds + 1280);      // [16]

    // per-row top-2 over this wave's 32 codes (C layout: col=lane&15 -> code,
    // row=(lane>>4)*4+reg -> z row)
    const float cn0 = cnorm[code0];
    const float cn1 = cnorm[code1];
    #pragma unroll
    for (int r = 0; r < 4; ++r) {
        const float va = cn0 - 2.f * acc0[r];
        const float vb = cn1 - 2.f * acc1[r];
        float v1, v2; int i1, i2;
        if (vb < va) { v1 = vb; i1 = code1; v2 = va; i2 = code0; }
        else         { v1 = va; i1 = code0; v2 = vb; i2 = code1; }
        #pragma unroll
        for (int m = 1; m < 16; m <<= 1) {
            const float o1 = __shfl_xor(v1, m, 64); const int oi1 = __shfl_xor(i1, m, 64);
            const float o2 = __shfl_xor(v2, m, 64); const int oi2 = __shfl_xor(i2, m, 64);
            if (lexlt(o1, oi1, v1, i1)) {
                if (lexlt(v1, i1, o2, oi2)) { v2 = v1; i2 = i1; }
                else                        { v2 = o2; i2 = oi2; }
                v1 = o1; i1 = oi1;
            } else if (lexlt(o1, oi1, v2, i2)) { v2 = o1; i2 = oi1; }
        }
        if (l15 == 0) {
            const int row = (lane >> 4) * 4 + r;
            smv1[wn * 16 + row] = v1; smi1[wn * 16 + row] = i1;
            smv2[wn * 16 + row] = v2; smi2[wn * 16 + row] = i2;
        }
    }
    __syncthreads();

    // merge 4 waves' sorted pairs -> global top-2 per row
    if (tid < 16) {
        float v1 = smv1[tid], v2 = smv2[tid];
        int   i1 = smi1[tid], i2 = smi2[tid];
        #pragma unroll
        for (int w = 1; w < 4; ++w) {
            const float o1 = smv1[w * 16 + tid], o2 = smv2[w * 16 + tid];
            const int  oi1 = smi1[w * 16 + tid], oi2 = smi2[w * 16 + tid];
            if (lexlt(o1, oi1, v1, i1)) {
                if (lexlt(v1, i1, o2, oi2)) { v2 = v1; i2 = i1; }
                else                        { v2 = o2; i2 = oi2; }
                v1 = o1; i1 = oi1;
            } else if (lexlt(o1, oi1, v2, i2)) { v2 = o1; i2 = oi1; }
        }
        kb2[tid * 2] = i1; kb2[tid * 2 + 1] = i2;
    }
    __syncthreads();

    // exact f32 refinement: 32 jobs (16 rows x 2 cands), 32-lane groups.
    // deciding compare reduces to cnorm - 2*dot (s2 identical both sides),
    // i.e. the formula that passed with absmax=0 in rounds 2-3.
    const int grp = tid >> 5, l31 = tid & 31;
    #pragma unroll
    for (int jt = 0; jt < 4; ++jt) {
        const int job = jt * 8 + grp;
        const int row = job >> 1;
        const int cand = kb2[row * 2 + (job & 1)];
        const float* zr = (row < 8) ? z + (size_t)(r0 + row) * D
                                    : zp + (size_t)(r0 + row - 8) * D;
        const float* cr = cb + (size_t)cand * D;
        float dot = 0.f;
        #pragma unroll
        for (int it = 0; it < 8; ++it) {
            const int col = l31 * 2 + it * 64;
            if (col < D) {
                const float2 a = *(const float2*)(zr + col);
                const float2 b = *(const float2*)(cr + col);
                dot = fmaf(a.x, b.x, fmaf(a.y, b.y, dot));
            }
        }
        #pragma unroll
        for (int m = 1; m < 32; m <<= 1) dot += __shfl_xor(dot, m, 64);
        if (l31 == 0) refd[job] = cnorm[cand] - 2.f * dot;
    }
    __syncthreads();
    if (tid < 16) {
        const float da = refd[tid * 2], db = refd[tid * 2 + 1];
        const int ia = kb2[tid * 2], ib = kb2[tid * 2 + 1];
        kbf[tid] = (db < da || (db == da && ib < ia)) ? ib : ia;
    }
    __syncthreads();

    // fused gather: 8 output rows x 32 lanes
    const int grow = tid >> 5;
    const int kz   = kbf[grow];
    const int kzp2 = kbf[8 + grow];
    const int pp   = pos[r0 + grow];
    const float* ra = cb + (size_t)kz * D;
    const float* rb = cb + (size_t)kzp2 * D;
    const float* rp = ph + (size_t)pp * D;
    float* ro = out + (size_t)(r0 + grow) * D;
    #pragma unroll
    for (int it = 0; it < 8; ++it) {
        const int col = l31 * 2 + it * 64;
        if (col < D) {
            const float2 a = *(const float2*)(ra + col);
            const float2 b = *(const float2*)(rb + col);
            const float2 p = *(const float2*)(rp + col);
            float2 o; o.x = a.x + b.x + p.x; o.y = a.y + b.y + p.y;
            *(float2*)(ro + col) = o;
        }
    }
}

// ================= fallback (round-3, proven): used if ws too small =======
__global__ void fb_cnorm(const float* __restrict__ cb, float* __restrict__ cnorm) {
    const int k = blockIdx.x, l = threadIdx.x;
    float s = 0.f;
    for (int i = l; i < D; i += 64) { float v = cb[(size_t)k * D + i]; s = fmaf(v, v, s); }
    #pragma unroll
    for (int m = 1; m < 64; m <<= 1) s += __shfl_xor(s, m, 64);
    if (l == 0) cnorm[k] = s;
}

__launch_bounds__(512, 2)
__global__ void fb_fused(const float* __restrict__ z, const float* __restrict__ zp,
                         const float* __restrict__ cb, const float* __restrict__ ph,
                         const int* __restrict__ pos, const float* __restrict__ cnorm,
                         float* __restrict__ out) {
    constexpr int LSW = 66;
    __shared__ float cb_lds[K_CODES][LSW];
    __shared__ float z_lds[32][LSW];
    __shared__ float sm[4][64][16];
    __shared__ int   kb[32];
    const int tid = threadIdx.x, lane = tid & 63;
    const int wu = __builtin_amdgcn_readfirstlane(tid >> 6);
    const int l32 = lane & 31, s = lane >> 5, wu3 = wu & 3, kh = wu >> 2;
    const int r0 = blockIdx.x * 16;
    const int rowb = wu3 * 8 + s * 4;
    float acc[4][4];
    #pragma unroll
    for (int j = 0; j < 4; ++j) {
        #pragma unroll
        for (int r = 0; r < 4; ++r) acc[j][r] = 0.f;
    }
    for (int kc = 0; kc < 8; ++kc) {
        const int k0 = kc * 64;
        #pragma unroll
        for (int i = 0; i < 2; ++i) {
            const int f2 = tid + 512 * i, m = f2 >> 5, kk = (f2 & 31) * 2, col = k0 + kk;
            const float* base = (m < 16) ? z + (size_t)(r0 + m) * D : zp + (size_t)(r0 + m - 16) * D;
            float2 v = make_float2(0.f, 0.f);
            if (col < D) v = *(const float2*)(base + col);
            *(float2*)&z_lds[m][kk] = v;
        }
        #pragma unroll
        for (int i = 0; i < 8; ++i) {
            const int f2 = tid + 512 * i, c = f2 >> 5, kk = (f2 & 31) * 2, col = k0 + kk;
            float2 v = make_float2(0.f, 0.f);
            if (col < D) v = *(const float2*)(cb + (size_t)c * D + col);
            *(float2*)&cb_lds[c][kk] = v;
        }
        __syncthreads();
        #pragma unroll
        for (int it = 0; it < 16; ++it) {
            const int col = kh * 32 + it * 2;
            float2 cv[4], zv[4];
            #pragma unroll
            for (int j = 0; j < 4; ++j) cv[j] = *(const float2*)&cb_lds[l32 + 32 * j][col];
            #pragma unroll
            for (int r = 0; r < 4; ++r) zv[r] = *(const float2*)&z_lds[rowb + r][col];
            #pragma unroll
            for (int j = 0; j < 4; ++j) {
                #pragma unroll
                for (int r = 0; r < 4; ++r)
                    acc[j][r] = fmaf(zv[r].y, cv[j].y, fmaf(zv[r].x, cv[j].x, acc[j][r]));
            }
        }
        __syncthreads();
    }
    if (kh == 1) {
        #pragma unroll
        for (int j = 0; j < 4; ++j) {
            #pragma unroll
            for (int r = 0; r < 4; ++r) sm[wu3][lane][j * 4 + r] = acc[j][r];
        }
    }
    __syncthreads();
    if (kh == 0) {
        #pragma unroll
        for (int j = 0; j < 4; ++j) {
            #pragma unroll
            for (int r = 0; r < 4; ++r) acc[j][r] += sm[wu3][lane][j * 4 + r];
        }
        float cnv[4];
        #pragma unroll
        for (int j = 0; j < 4; ++j) cnv[j] = cnorm[l32 + 32 * j];
        #pragma unroll
        for (int r = 0; r < 4; ++r) {
            float bv = cnv[0] - 2.f * acc[0][r]; int bi = l32;
            #pragma unroll
            for (int j = 1; j < 4; ++j) {
                const float d = cnv[j] - 2.f * acc[j][r];
                if (d < bv) { bv = d; bi = l32 + 32 * j; }
            }
            #pragma unroll
            for (int m = 1; m < 32; m <<= 1) {
                const float ov = __shfl_xor(bv, m, 64);
                const int oi = __shfl_xor(bi, m, 64);
                if (ov < bv || (ov == bv && oi < bi)) { bv = ov; bi = oi; }
            }
            if (l32 == 0) kb[rowb + r] = bi;
        }
    }
    __syncthreads();
    const int i = tid >> 5, g32 = tid & 31;
    const int kz = kb[i], kzp = kb[16 + i], pp = pos[r0 + i];
    const float* a = cb + (size_t)kz * D;
    const float* b = cb + (size_t)kzp * D;
    const float* e = ph + (size_t)pp * D;
    float* o = out + (size_t)(r0 + i) * D;
    #pragma unroll
    for (int itg = 0; itg < 8; ++itg) {
        const int col = g32 * 2 + itg * 64;
        if (col < D) {
            const float2 va = *(const float2*)(a + col);
            const float2 vb = *(const float2*)(b + col);
            const float2 ve = *(const float2*)(e + col);
            float2 vo; vo.x = va.x + vb.x + ve.x; vo.y = va.y + vb.y + ve.y;
            *(float2*)(o + col) = vo;
        }
    }
}

extern "C" void kernel_launch(void* const* d_in, const int* in_sizes, int n_in,
                              void* d_out, int out_size, void* d_ws, size_t ws_size,
                              hipStream_t stream) {
    const float* z  = (const float*)d_in[0];
    const float* zp = (const float*)d_in[1];
    const float* cb = (const float*)d_in[2];
    const float* ph = (const float*)d_in[3];
    const int*   pos = (const int*)d_in[4];
    float* out = (float*)d_out;

    float* cnorm = (float*)d_ws;
    char*  cbimg = (char*)d_ws + 512;

    if (ws_size >= WS_NEED) {
        prep_kernel<<<K_CODES, 64, 0, stream>>>(cb, cnorm, cbimg);
        main_kernel<<<BHALF / 8, 256, 0, stream>>>(z, zp, cb, ph, pos, cnorm, cbimg, out);
    } else {
        fb_cnorm<<<K_CODES, 64, 0, stream>>>(cb, cnorm);
        fb_fused<<<BHALF / 16, 512, 0, stream>>>(z, zp, cb, ph, pos, cnorm, out);
    }
}